// Round 1
// baseline (499.538 us; speedup 1.0000x reference)
//
#include <hip/hip_runtime.h>
#include <hip/hip_bf16.h>
#include <stdint.h>

typedef __bf16 bf16_t;
typedef bf16_t bf16x4 __attribute__((ext_vector_type(4)));
typedef bf16_t bf16x8 __attribute__((ext_vector_type(8)));
typedef float f32x4 __attribute__((ext_vector_type(4)));

#define GAS __attribute__((address_space(1)))
#define LAS __attribute__((address_space(3)))

__device__ __forceinline__ void async_load16(const void* g, void* l) {
    __builtin_amdgcn_global_load_lds((const GAS void*)g, (LAS void*)l, 16, 0, 0);
}

// ---------- phase 1 (merged, grid-stride): cast x->bf16  +  dequant W->bf16 ----------
// Rewritten: 2048 cast blocks + 512 dequant blocks, grid-stride, 16B stores on
// both paths (was: 40960 one-shot blocks, 8B stores on cast path, ~1.1 TB/s).
__global__ __launch_bounds__(256) void prep_kernel(
    const float* __restrict__ x, bf16_t* __restrict__ xb,
    const int* __restrict__ wp, const float* __restrict__ cen,
    const float* __restrict__ scl, bf16_t* __restrict__ W,
    int castBlocks, long nCastChunks, int nDeqChunks)
{
    if ((int)blockIdx.x < castBlocks) {
        // one chunk = 8 f32 in (32B) -> 8 bf16 out (16B)
        long idx    = (long)blockIdx.x * blockDim.x + threadIdx.x;
        long stride = (long)castBlocks * blockDim.x;
        const float4* xv = (const float4*)x;
        bf16x8* xo = (bf16x8*)xb;
        for (long t = idx; t < nCastChunks; t += stride) {
            float4 a = xv[2 * t];
            float4 b = xv[2 * t + 1];
            bf16x8 o;
            o[0] = (bf16_t)a.x; o[1] = (bf16_t)a.y; o[2] = (bf16_t)a.z; o[3] = (bf16_t)a.w;
            o[4] = (bf16_t)b.x; o[5] = (bf16_t)b.y; o[6] = (bf16_t)b.z; o[7] = (bf16_t)b.w;
            xo[t] = o;
        }
    } else {
        __shared__ float c[16];
        if (threadIdx.x < 16) c[threadIdx.x] = cen[threadIdx.x];
        __syncthreads();
        int  nb     = (int)gridDim.x - castBlocks;
        long idx    = (long)((int)blockIdx.x - castBlocks) * blockDim.x + threadIdx.x;
        long stride = (long)nb * blockDim.x;
        const int4* wv = (const int4*)wp;
        bf16x8* wo = (bf16x8*)W;
        for (long t = idx; t < (long)nDeqChunks; t += stride) {
            int4 v = wv[t];                 // 4 packed int32 (1 byte-code each) = 8 weights
            long p   = t << 2;              // packed index (4/thread, aligned -> one scale block)
            int  o   = (int)(p >> 11);      // row (2048 packed per row)
            int  pin = (int)p & 2047;
            float s = scl[(o << 6) + (pin >> 5)];   // 64 scale blocks/row, 32 packed each
            int vv[4] = {v.x, v.y, v.z, v.w};
            bf16x8 outv;
#pragma unroll
            for (int i = 0; i < 4; ++i) {
                int b = vv[i];
                outv[2 * i]     = (bf16_t)(c[(b >> 4) & 15] * s);
                outv[2 * i + 1] = (bf16_t)(c[b & 15] * s);
            }
            wo[t] = outv;
        }
    }
}

// ---------------- phase 2: bf16 NT GEMM, BK=64 (UNCHANGED from 475.9us version) ----------------
// 128x128 tile, BK=64 (32 KB LDS, 2 barriers per 64-K step -> 32 MFMA/wave per
// barrier-pair). XOR swizzle at 16B-chunk granularity: (row,kc) -> slot
// row*8 + (kc ^ (row&7)); staging permutes global kc (LDS dest fixed lane*16).
#define BM 128
#define BN 128
#define BK 64

__global__ __launch_bounds__(256, 4) void gemm_bf16_nt(
    const bf16_t* __restrict__ A, const bf16_t* __restrict__ B,
    float* __restrict__ C, int M, int N, int K)
{
    __shared__ bf16_t lA[BM * BK];   // 16 KB
    __shared__ bf16_t lB[BN * BK];   // 16 KB

    const int tid  = threadIdx.x;
    const int wave = tid >> 6;
    const int lane = tid & 63;
    const int wm   = (wave >> 1) * 64;
    const int wn   = (wave & 1) * 64;

    const long m0 = (long)blockIdx.y * BM;
    const long n0 = (long)blockIdx.x * BN;

    // staging: 1024 chunks per matrix, 4 rounds of 256 threads.
    // slot s = r*256 + tid : row = s>>3, kc_slot = s&7, global kc = kc_slot^(row&7)
    const bf16_t* aP[4];
    const bf16_t* bP[4];
    int ldsOff[4];
#pragma unroll
    for (int r = 0; r < 4; ++r) {
        int s   = r * 256 + tid;
        int row = s >> 3;
        int kg  = (s & 7) ^ (row & 7);
        aP[r] = A + (m0 + row) * K + kg * 8;
        bP[r] = B + (n0 + row) * K + kg * 8;
        ldsOff[r] = (r * 256 + wave * 64) * 8;   // wave-uniform elem offset
    }

    // fragment reads: A[m=lane&15][k=(lane>>4)*8+j] per 32-K half
    const int qm = lane & 15;
    const int kcb = lane >> 4;          // 0..3
    const int swk = qm & 7;             // swizzle key (row&7 == qm&7 here)
    const bf16_t* pa = lA + (wm + qm) * BK;
    const bf16_t* pb = lB + (wn + qm) * BK;
    const int co0 = (kcb ^ swk) * 8;          // half t=0 chunk offset (elems)
    const int co1 = ((kcb + 4) ^ swk) * 8;    // half t=1

    f32x4 acc[4][4] = {};

    for (int k0 = 0; k0 < K; k0 += BK) {
#pragma unroll
        for (int r = 0; r < 4; ++r) async_load16(aP[r] + k0, lA + ldsOff[r]);
#pragma unroll
        for (int r = 0; r < 4; ++r) async_load16(bP[r] + k0, lB + ldsOff[r]);
        __syncthreads();

        bf16x8 af[4], bfv[4];
        // half 0
#pragma unroll
        for (int i = 0; i < 4; ++i) af[i] = *(const bf16x8*)(pa + i * 16 * BK + co0);
#pragma unroll
        for (int j = 0; j < 4; ++j) bfv[j] = *(const bf16x8*)(pb + j * 16 * BK + co0);
#pragma unroll
        for (int i = 0; i < 4; ++i)
#pragma unroll
            for (int j = 0; j < 4; ++j)
                acc[i][j] = __builtin_amdgcn_mfma_f32_16x16x32_bf16(af[i], bfv[j], acc[i][j], 0, 0, 0);
        // half 1
#pragma unroll
        for (int i = 0; i < 4; ++i) af[i] = *(const bf16x8*)(pa + i * 16 * BK + co1);
#pragma unroll
        for (int j = 0; j < 4; ++j) bfv[j] = *(const bf16x8*)(pb + j * 16 * BK + co1);
#pragma unroll
        for (int i = 0; i < 4; ++i)
#pragma unroll
            for (int j = 0; j < 4; ++j)
                acc[i][j] = __builtin_amdgcn_mfma_f32_16x16x32_bf16(af[i], bfv[j], acc[i][j], 0, 0, 0);
        __syncthreads();
    }

    // C/D layout: col = lane&15, row = (lane>>4)*4 + reg   [m89-verified]
    const int crow = (lane >> 4) * 4;
    const int ccol = lane & 15;
#pragma unroll
    for (int i = 0; i < 4; ++i)
#pragma unroll
        for (int r = 0; r < 4; ++r) {
            float* cp = C + (m0 + wm + i * 16 + crow + r) * N + (n0 + wn + ccol);
#pragma unroll
            for (int j = 0; j < 4; ++j)
                cp[j * 16] = acc[i][j][r];
        }
}

// ---------------- fallback (only if ws too small): fused, slow, correct ----------------
__global__ void fallback_qgemm(const float* __restrict__ x, const int* __restrict__ wp,
                               const float* __restrict__ cen, const float* __restrict__ scl,
                               float* __restrict__ out, int M, int N, int Kp) {
    __shared__ float c[16];
    if (threadIdx.x < 16) c[threadIdx.x] = cen[threadIdx.x];
    __syncthreads();
    int n = blockIdx.x * blockDim.x + threadIdx.x;
    int m = blockIdx.y;
    if (n >= N) return;
    const float* xr = x + (long)m * (Kp * 2);
    const int*   wr = wp + (long)n * Kp;
    int nb = Kp / 32;
    float acc = 0.f;
    for (int b = 0; b < nb; ++b) {
        float s  = scl[n * nb + b];
        float pa = 0.f;
        for (int j = 0; j < 32; ++j) {
            int v = wr[b * 32 + j];
            pa += xr[(b * 32 + j) * 2]     * c[(v >> 4) & 15]
                + xr[(b * 32 + j) * 2 + 1] * c[v & 15];
        }
        acc += s * pa;
    }
    out[(long)m * N + n] = acc;
}

extern "C" void kernel_launch(void* const* d_in, const int* in_sizes, int n_in,
                              void* d_out, int out_size, void* d_ws, size_t ws_size,
                              hipStream_t stream) {
    const float* x   = (const float*)d_in[0];
    const int*   wp  = (const int*)d_in[1];
    const float* cen = (const float*)d_in[2];
    const float* scl = (const float*)d_in[3];
    float* out = (float*)d_out;

    const int  IN  = 4096;
    const int  OUT = 4096;
    const long M   = (long)in_sizes[0] / IN;   // 8192

    size_t need = (size_t)(M * IN + (long)OUT * IN) * sizeof(bf16_t);  // 96 MB
    if (ws_size >= need) {
        bf16_t* xb = (bf16_t*)d_ws;
        bf16_t* Wb = xb + M * IN;
        const int castBlocks = 2048;
        const int deqBlocks  = 512;
        long nCastChunks = M * IN / 8;               // 8 f32 per chunk
        int  nDeqChunks  = OUT * (IN / 2) / 4;       // 4 int32 per chunk
        prep_kernel<<<dim3(castBlocks + deqBlocks), dim3(256), 0, stream>>>(
            x, xb, wp, cen, scl, Wb, castBlocks, nCastChunks, nDeqChunks);
        dim3 grid(OUT / BN, (unsigned)(M / BM));
        gemm_bf16_nt<<<grid, dim3(256), 0, stream>>>(xb, Wb, out, (int)M, OUT, IN);
    } else {
        dim3 grid(OUT / 256, (unsigned)M);
        fallback_qgemm<<<grid, dim3(256), 0, stream>>>(x, wp, cen, scl, out, (int)M, OUT, IN / 2);
    }
}